// Round 1
// baseline (50.709 us; speedup 1.0000x reference)
//
#include <hip/hip_runtime.h>

// Problem constants from reference: B=16, S=4096, F=1024, units fp32, mask int32.
#define B_ 16
#define S_ 4096
#define F_ 1024
#define F4_ (F_ / 4)   // float4 per output row = 256

// One block per batch row. 1024 threads; each thread scans 4 mask elems (int4).
// Produces src[b*S_ + p] = s for the p-th masked subtoken of row b, and lens[b].
__global__ __launch_bounds__(1024) void pos_kernel(const int* __restrict__ mask,
                                                   int* __restrict__ src,
                                                   int* __restrict__ lens) {
    const int b   = blockIdx.x;
    const int tid = threadIdx.x;

    const int4 m = ((const int4*)(mask + b * S_))[tid];
    const int local = m.x + m.y + m.z + m.w;

    const int lane = tid & 63;
    const int wid  = tid >> 6;

    // wave-inclusive scan of per-thread sums
    int incl = local;
#pragma unroll
    for (int d = 1; d < 64; d <<= 1) {
        int n = __shfl_up(incl, d, 64);
        if (lane >= d) incl += n;
    }

    __shared__ int wsum[16];
    __shared__ int woff[17];
    if (lane == 63) wsum[wid] = incl;
    __syncthreads();
    if (tid == 0) {
        int acc = 0;
#pragma unroll
        for (int w = 0; w < 16; ++w) { woff[w] = acc; acc += wsum[w]; }
        woff[16] = acc;
        lens[b] = acc;
    }
    __syncthreads();

    int p = woff[wid] + (incl - local);   // exclusive prefix for this thread
    const int s0 = tid * 4;
    int* srow = src + b * S_;
    if (m.x) srow[p++] = s0;
    if (m.y) srow[p++] = s0 + 1;
    if (m.z) srow[p++] = s0 + 2;
    if (m.w) srow[p]   = s0 + 3;
}

// One block per output token row (grid: T x B). 256 threads, one float4 each.
__global__ __launch_bounds__(F4_) void scatter_kernel(const float4* __restrict__ units,
                                                      const int* __restrict__ src,
                                                      const int* __restrict__ lens,
                                                      float4* __restrict__ out, int T) {
    const int t = blockIdx.x;
    const int b = blockIdx.y;

    float4 v = make_float4(0.f, 0.f, 0.f, 0.f);
    const int len = lens[b];   // scalar (wave-uniform) load, broadcast
    if (t < len) {
        const int s = src[b * S_ + t];
        v = units[((size_t)(b * S_ + s)) * F4_ + threadIdx.x];
    }
    out[((size_t)b * (size_t)T + t) * F4_ + threadIdx.x] = v;
}

extern "C" void kernel_launch(void* const* d_in, const int* in_sizes, int n_in,
                              void* d_out, int out_size, void* d_ws, size_t ws_size,
                              hipStream_t stream) {
    const float* units = (const float*)d_in[0];
    const int*   mask  = (const int*)d_in[1];
    float*       out   = (float*)d_out;

    const int T = out_size / (B_ * F_);   // harness sized d_out as B*T*F

    int* src  = (int*)d_ws;               // B_*S_ ints
    int* lens = src + B_ * S_;            // B_ ints

    pos_kernel<<<B_, 1024, 0, stream>>>(mask, src, lens);

    dim3 grid((unsigned)T, B_);
    scatter_kernel<<<grid, F4_, 0, stream>>>((const float4*)units, src, lens,
                                             (float4*)out, T);
}